// Round 4
// baseline (402.618 us; speedup 1.0000x reference)
//
#include <hip/hip_runtime.h>
#include <hip/hip_bf16.h>

// Problem constants (fixed by reference)
#define N_ROWS 200000
#define DIMS   128
#define E_UPD  100000
#define TILE   64
#define NTILES (N_ROWS / TILE)   // 3125, exact
#define MSTRIDE 136              // 128 + 8 pad shorts (272 B = 16*17: 16B-aligned rows, 4-bank skew)
#define HSTRIDE 136
#define MAIN_GRID 768            // 3 blocks/CU * 256 CUs resident; work-stealing balances

typedef float f32x4 __attribute__((ext_vector_type(4)));
typedef __bf16 bf16x8 __attribute__((ext_vector_type(8)));
typedef unsigned short u16x8 __attribute__((ext_vector_type(8)));

static __device__ __forceinline__ unsigned short f2b(float f) {
    __hip_bfloat16 b = __float2bfloat16(f);
    return __builtin_bit_cast(unsigned short, b);
}

__global__ void fill_inv(int* inv, int* counter) {
    int i = blockIdx.x * blockDim.x + threadIdx.x;
    if (i < N_ROWS) inv[i] = -1;
    if (i == 0) counter[0] = 0;
}

__global__ void scatter_inv(const int* __restrict__ src, int* __restrict__ inv) {
    int e = blockIdx.x * blockDim.x + threadIdx.x;
    if (e < E_UPD) inv[src[e]] = e;
}

// min 6 waves/EU: VGPR capped at ~85 — fits 48 frag + 17 prefetch + temps.
// (Round-1 lesson: min 8 -> 64-VGPR cap spilled the 48-VGPR fragment set; WRITE_SIZE +83 MB.)
__launch_bounds__(512, 6)
__global__ void ctdg_main(
    const float* __restrict__ memory,      // [N][129]
    const float* __restrict__ last_update, // [N]
    const float* __restrict__ umsg,        // [E][129]
    const float* __restrict__ uts,         // [E]
    const float* __restrict__ semb,        // [N][128]
    const float* __restrict__ W1,          // [256][128]
    const float* __restrict__ b1,          // [128]
    const float* __restrict__ W2,          // [128][128]
    const float* __restrict__ b2,          // [128]
    const float* __restrict__ e_lamb_p,    // [1]
    const float* __restrict__ now_p,       // [1]
    const int*   __restrict__ inv,         // [N] (ws)
    int*         __restrict__ counter,     // work-steal counter (ws)
    float*       __restrict__ out)         // [N][128] fp32
{
    // LDS ~35.9 KB -> 4 blocks/CU by LDS; wave cap (6/SIMD) gives 3.
    __shared__ __align__(16) unsigned short msum_s[TILE][MSTRIDE];
    __shared__ __align__(16) unsigned short h1s[TILE][HSTRIDE];
    __shared__ float rcinv[TILE];
    __shared__ float rscale[2][TILE];   // parity-buffered: written A(i), read C(i)
    __shared__ int   s_next[2];         // parity-buffered tile broadcast
    // RACE FIX (round 3): single s_tile had write@A(i) in the same barrier
    // interval as the prologue read (and C(i-1)) -> possible divergent `tile`
    // -> barrier deadlock. Parity slots put >=1 barrier between every
    // write and every read of the same slot, both directions.

    const int tid  = threadIdx.x;
    const int lane = tid & 63;
    const int wave = tid >> 6;     // 0..7 — owns output cols [wave*16, wave*16+16)
    const int quad = lane >> 4;    // 0..3
    const int l16  = lane & 15;
    const int wn   = wave * 16;

    // ---- persistent B-fragments: B[k = t*32 + quad*8 + j][n = wn + l16] ----
    // Split-W1: feat@W1 = ci*(msum@W1[0:128]) + msum@W1[128:256]
    u16x8 w1a[4];   // W1 rows   0..127  (ci applied post-MFMA in f32)
    u16x8 w1b[4];   // W1 rows 128..255
    u16x8 w2f[4];
    #pragma unroll
    for (int t = 0; t < 4; ++t) {
        #pragma unroll
        for (int j = 0; j < 8; ++j) {
            const int kr = t*32 + quad*8 + j;
            w1a[t][j] = f2b(W1[kr*128 + wn + l16]);
            w1b[t][j] = f2b(W1[(128 + kr)*128 + wn + l16]);
            w2f[t][j] = f2b(W2[kr*128 + wn + l16]);
        }
    }
    const float b1v   = b1[wn + l16];
    const float b2v   = b2[wn + l16];
    const float el    = e_lamb_p[0];
    const float nowt  = now_p[0];
    const float inv30 = 1.0f / 30.0f;   // 1/LAMB == 1/OUTPUT

    const int r = tid >> 3;   // row in tile (0..63)
    const int s = tid & 7;    // col phase (8 threads/row)

    // ---- prologue ("iteration -1", slot 0): first tile + prefetch its rows ----
    if (tid == 0) s_next[0] = atomicAdd(counter, 1);
    __syncthreads();
    int tile = s_next[0];

    float pm0[8], pm1[8];   // prefetched memory-row pairs for the NEXT stage phase
    int   pe = -1;          // prefetched inv[g]
    if (tile < NTILES) {
        const int g = tile*TILE + r;
        pe = inv[g];
        const float* mrow = memory + (size_t)g*129;
        #pragma unroll
        for (int j = 0; j < 8; ++j) {
            const int c = 2*s + 16*j;
            pm0[j] = mrow[c];
            pm1[j] = mrow[c+1];
        }
    }

    int it = 0;   // iteration parity for rscale / s_next
    while (tile < NTILES) {
        const int row0 = tile * TILE;
        const int par  = it & 1;
        const int nxt  = par ^ 1;

        // ==== interval A: grab next tile into slot `nxt`; stage msum from regs ====
        if (tid == 0) s_next[nxt] = atomicAdd(counter, 1);
        {
            const int g  = row0 + r;
            const int e  = pe;
            const float lu = last_update[g];
            const float mc = memory[(size_t)g*129 + 128];
            float d, cnt, lun;
            if (e >= 0) {
                const float ts = uts[e];
                d   = __expf((lu - ts) * inv30);
                cnt = fmaf(mc, d, umsg[(size_t)e*129 + 128]);
                lun = ts;
            } else {
                d = 1.0f; cnt = mc; lun = lu;
            }
            if (s == 0) {
                rcinv[r]       = 1.0f / (cnt + 1e-10f);
                rscale[par][r] = __expf((lun - nowt) * inv30);
            }
            if (e >= 0) {
                const float* grow = umsg + (size_t)e*129;
                #pragma unroll
                for (int j = 0; j < 8; ++j) {
                    const int c = 2*s + 16*j;
                    const float m0 = fmaf(pm0[j], d, grow[c]);
                    const float m1 = fmaf(pm1[j], d, grow[c+1]);
                    *(unsigned*)&msum_s[r][c] = (unsigned)f2b(m0) | ((unsigned)f2b(m1) << 16);
                }
            } else {
                #pragma unroll
                for (int j = 0; j < 8; ++j) {
                    const int c = 2*s + 16*j;
                    *(unsigned*)&msum_s[r][c] = (unsigned)f2b(pm0[j]) | ((unsigned)f2b(pm1[j]) << 16);
                }
            }
        }
        __syncthreads();   // bar1: msum/rcinv/rscale ready; publishes s_next[nxt]

        // ==== interval B: GEMM1 -> h1s ====
        const int tn = s_next[nxt];   // slot nxt next written at A(i+2): 3 barriers away
        #pragma unroll
        for (int mt = 0; mt < 4; ++mt) {
            f32x4 aP = {0.f, 0.f, 0.f, 0.f};
            f32x4 aQ = {0.f, 0.f, 0.f, 0.f};
            const int mrow = mt*16 + l16;   // A: m = lane&15
            #pragma unroll
            for (int k = 0; k < 4; ++k) {
                u16x8 a = *(const u16x8*)&msum_s[mrow][k*32 + quad*8];
                aP = __builtin_amdgcn_mfma_f32_16x16x32_bf16(
                        __builtin_bit_cast(bf16x8, a),
                        __builtin_bit_cast(bf16x8, w1a[k]), aP, 0, 0, 0);
                aQ = __builtin_amdgcn_mfma_f32_16x16x32_bf16(
                        __builtin_bit_cast(bf16x8, a),
                        __builtin_bit_cast(bf16x8, w1b[k]), aQ, 0, 0, 0);
            }
            #pragma unroll
            for (int rr = 0; rr < 4; ++rr) {   // C: col = lane&15, row = quad*4 + rr
                const int row = mt*16 + quad*4 + rr;
                float v = fmaf(rcinv[row], aP[rr], aQ[rr]) + b1v;
                v = (v >= 0.f) ? v : 0.01f * v;
                h1s[row][wn + l16] = f2b(v);
            }
        }
        __syncthreads();   // bar2: h1s ready

        // ==== interval C: prefetch next tile's rows (flies under GEMM2+epilogue),
        //                  then GEMM2 + fused epilogue ====
        if (tn < NTILES) {
            const int g2 = tn*TILE + r;
            pe = inv[g2];
            const float* mrow2 = memory + (size_t)g2*129;
            #pragma unroll
            for (int j = 0; j < 8; ++j) {
                const int c = 2*s + 16*j;
                pm0[j] = mrow2[c];
                pm1[j] = mrow2[c+1];
            }
        }
        #pragma unroll
        for (int mt = 0; mt < 4; ++mt) {
            f32x4 acc = {0.f, 0.f, 0.f, 0.f};
            const int mrow = mt*16 + l16;
            #pragma unroll
            for (int k = 0; k < 4; ++k) {
                u16x8 a = *(const u16x8*)&h1s[mrow][k*32 + quad*8];
                acc = __builtin_amdgcn_mfma_f32_16x16x32_bf16(
                        __builtin_bit_cast(bf16x8, a),
                        __builtin_bit_cast(bf16x8, w2f[k]), acc, 0, 0, 0);
            }
            #pragma unroll
            for (int rr = 0; rr < 4; ++rr) {
                const int row = mt*16 + quad*4 + rr;
                const int g = row0 + row;
                float v = acc[rr] + b2v;
                v = (v >= 0.f) ? v : 0.01f * v;
                v *= rscale[par][row];                  // * exp((lu'-now)/OUTPUT)
                const float sv = semb[(size_t)g*128 + wn + l16];
                out[(size_t)g*128 + wn + l16] = el * sv + (1.0f - el) * v;
            }
        }
        // No C->A barrier needed: msum WAR guarded by bar2 (last readers in B);
        // h1s WAR guarded by next bar1; rscale & s_next parity-buffered.
        tile = tn;
        ++it;
    }
}

extern "C" void kernel_launch(void* const* d_in, const int* in_sizes, int n_in,
                              void* d_out, int out_size, void* d_ws, size_t ws_size,
                              hipStream_t stream) {
    const float* memory      = (const float*)d_in[0];
    const float* last_update = (const float*)d_in[1];
    const float* umsg        = (const float*)d_in[2];
    const float* uts         = (const float*)d_in[3];
    const float* semb        = (const float*)d_in[4];
    const float* W1          = (const float*)d_in[5];
    const float* b1          = (const float*)d_in[6];
    const float* W2          = (const float*)d_in[7];
    const float* b2          = (const float*)d_in[8];
    const float* e_lamb      = (const float*)d_in[9];
    const float* nowt        = (const float*)d_in[10];
    const int*   src         = (const int*)d_in[11];

    int* inv     = (int*)d_ws;            // N ints
    int* counter = inv + N_ROWS;          // 1 int (work-steal)
    float* out   = (float*)d_out;         // fp32 — reference output dtype

    fill_inv<<<(N_ROWS + 255) / 256, 256, 0, stream>>>(inv, counter);
    scatter_inv<<<(E_UPD + 255) / 256, 256, 0, stream>>>(src, inv);
    ctdg_main<<<MAIN_GRID, 512, 0, stream>>>(memory, last_update, umsg, uts, semb,
                                             W1, b1, W2, b2, e_lamb, nowt,
                                             inv, counter, out);
}

// Round 5
// 313.708 us; speedup vs baseline: 1.2834x; 1.2834x over previous
//
#include <hip/hip_runtime.h>
#include <hip/hip_bf16.h>

// Problem constants (fixed by reference)
#define N_ROWS 200000
#define DIMS   128
#define E_UPD  100000
#define TILE   64
#define NTILES (N_ROWS / TILE)   // 3125, exact
#define MSTRIDE 136              // 128 + 8 pad shorts (272 B = 16*17: 16B-aligned rows, 4-bank skew)
#define HSTRIDE 136
#define MAIN_GRID 768            // up to 3 blocks/CU resident; work-stealing balances

typedef float f32x4 __attribute__((ext_vector_type(4)));
typedef __bf16 bf16x8 __attribute__((ext_vector_type(8)));
typedef unsigned short u16x8 __attribute__((ext_vector_type(8)));

static __device__ __forceinline__ unsigned short f2b(float f) {
    __hip_bfloat16 b = __float2bfloat16(f);
    return __builtin_bit_cast(unsigned short, b);
}

__global__ void fill_inv(int* inv, int* counter) {
    int i = blockIdx.x * blockDim.x + threadIdx.x;
    if (i < N_ROWS) inv[i] = -1;
    if (i == 0) counter[0] = 0;
}

__global__ void scatter_inv(const int* __restrict__ src, int* __restrict__ inv) {
    int e = blockIdx.x * blockDim.x + threadIdx.x;
    if (e < E_UPD) inv[src[e]] = e;
}

// NOTE: plain __launch_bounds__(512) ONLY. Empirical rule from rounds 1 & 4:
// any min-waves 2nd argument makes the allocator collapse VGPRs far below the
// occupancy cap (min8->32, min6->40) and spill the 48-VGPR weight set
// (WRITE_SIZE +150 MB, +60% dur). Round 0 with no 2nd arg: 68 VGPR, no spill.
__launch_bounds__(512)
__global__ void ctdg_main(
    const float* __restrict__ memory,      // [N][129]
    const float* __restrict__ last_update, // [N]
    const float* __restrict__ umsg,        // [E][129]
    const float* __restrict__ uts,         // [E]
    const float* __restrict__ semb,        // [N][128]
    const float* __restrict__ W1,          // [256][128]
    const float* __restrict__ b1,          // [128]
    const float* __restrict__ W2,          // [128][128]
    const float* __restrict__ b2,          // [128]
    const float* __restrict__ e_lamb_p,    // [1]
    const float* __restrict__ now_p,       // [1]
    const int*   __restrict__ inv,         // [N] (ws)
    int*         __restrict__ counter,     // work-steal counter (ws)
    float*       __restrict__ out)         // [N][128] fp32
{
    // LDS ~35.9 KB
    __shared__ __align__(16) unsigned short msum_s[TILE][MSTRIDE];
    __shared__ __align__(16) unsigned short h1s[TILE][HSTRIDE];
    __shared__ float rcinv[TILE];
    __shared__ float rscale[2][TILE];   // parity-buffered: written A(i), read C(i)
    __shared__ int   s_next[2];         // parity-buffered tile broadcast (race fix, round 3)

    const int tid  = threadIdx.x;
    const int lane = tid & 63;
    const int wave = tid >> 6;     // 0..7 — owns output cols [wave*16, wave*16+16)
    const int quad = lane >> 4;    // 0..3
    const int l16  = lane & 15;
    const int wn   = wave * 16;

    // ---- persistent B-fragments: B[k = t*32 + quad*8 + j][n = wn + l16] ----
    // Split-W1: feat@W1 = ci*(msum@W1[0:128]) + msum@W1[128:256]
    u16x8 w1a[4];   // W1 rows   0..127  (ci applied post-MFMA in f32)
    u16x8 w1b[4];   // W1 rows 128..255
    u16x8 w2f[4];
    #pragma unroll
    for (int t = 0; t < 4; ++t) {
        #pragma unroll
        for (int j = 0; j < 8; ++j) {
            const int kr = t*32 + quad*8 + j;
            w1a[t][j] = f2b(W1[kr*128 + wn + l16]);
            w1b[t][j] = f2b(W1[(128 + kr)*128 + wn + l16]);
            w2f[t][j] = f2b(W2[kr*128 + wn + l16]);
        }
    }
    const float b1v   = b1[wn + l16];
    const float b2v   = b2[wn + l16];
    const float el    = e_lamb_p[0];
    const float nowt  = now_p[0];
    const float inv30 = 1.0f / 30.0f;   // 1/LAMB == 1/OUTPUT

    const int r  = tid >> 3;    // row in tile (0..63)
    const int s  = tid & 7;     // col segment: this thread owns cols [16s, 16s+16)
    const int c0 = s * 16;

    // ---- prologue ("iteration -1", slot 0): first tile + full prefetch ----
    if (tid == 0) s_next[0] = atomicAdd(counter, 1);
    __syncthreads();
    int tile = s_next[0];

    float pm[16];               // prefetched memory row segment (fp32)
    int   pe  = -1;             // prefetched inv[g]
    float plu = 0.f, pmc = 0.f; // prefetched last_update[g], memory[g][128]
    float pts = 0.f, pgc = 0.f; // prefetched uts[e], umsg[e][128]
    if (tile < NTILES) {
        const int g = tile*TILE + r;
        pe  = inv[g];
        plu = last_update[g];
        pmc = memory[(size_t)g*129 + 128];
        const float* mrow = memory + (size_t)g*129 + c0;
        #pragma unroll
        for (int j = 0; j < 16; ++j) pm[j] = mrow[j];
        if (pe >= 0) {
            pts = uts[pe];
            pgc = umsg[(size_t)pe*129 + 128];
        }
    }

    int it = 0;   // iteration parity for rscale / s_next
    while (tile < NTILES) {
        const int row0 = tile * TILE;
        const int par  = it & 1;
        const int nxt  = par ^ 1;

        // ==== interval A: grab next tile into slot `nxt`; stage msum from regs ====
        if (tid == 0) s_next[nxt] = atomicAdd(counter, 1);
        {
            const int e = pe;
            float d, cnt, lun;
            if (e >= 0) {
                d   = __expf((plu - pts) * inv30);
                cnt = fmaf(pmc, d, pgc);
                lun = pts;
            } else {
                d = 1.0f; cnt = pmc; lun = plu;
            }
            if (s == 0) {
                rcinv[r]       = 1.0f / (cnt + 1e-10f);
                rscale[par][r] = __expf((lun - nowt) * inv30);
            }
            if (e >= 0) {
                const float* grow = umsg + (size_t)e*129 + c0;
                #pragma unroll
                for (int j = 0; j < 8; ++j) {
                    const float m0 = fmaf(pm[2*j],   d, grow[2*j]);
                    const float m1 = fmaf(pm[2*j+1], d, grow[2*j+1]);
                    *(unsigned*)&msum_s[r][c0 + 2*j] =
                        (unsigned)f2b(m0) | ((unsigned)f2b(m1) << 16);
                }
            } else {
                #pragma unroll
                for (int j = 0; j < 8; ++j) {
                    *(unsigned*)&msum_s[r][c0 + 2*j] =
                        (unsigned)f2b(pm[2*j]) | ((unsigned)f2b(pm[2*j+1]) << 16);
                }
            }
        }
        __syncthreads();   // bar1: msum/rcinv/rscale ready; publishes s_next[nxt]

        // ==== interval B: GEMM1 -> h1s ====
        const int tn = s_next[nxt];   // slot nxt next written at A(i+2): 3 barriers away
        #pragma unroll
        for (int mt = 0; mt < 4; ++mt) {
            f32x4 aP = {0.f, 0.f, 0.f, 0.f};
            f32x4 aQ = {0.f, 0.f, 0.f, 0.f};
            const int mrow = mt*16 + l16;   // A: m = lane&15
            #pragma unroll
            for (int k = 0; k < 4; ++k) {
                u16x8 a = *(const u16x8*)&msum_s[mrow][k*32 + quad*8];
                aP = __builtin_amdgcn_mfma_f32_16x16x32_bf16(
                        __builtin_bit_cast(bf16x8, a),
                        __builtin_bit_cast(bf16x8, w1a[k]), aP, 0, 0, 0);
                aQ = __builtin_amdgcn_mfma_f32_16x16x32_bf16(
                        __builtin_bit_cast(bf16x8, a),
                        __builtin_bit_cast(bf16x8, w1b[k]), aQ, 0, 0, 0);
            }
            #pragma unroll
            for (int rr = 0; rr < 4; ++rr) {   // C: col = lane&15, row = quad*4 + rr
                const int row = mt*16 + quad*4 + rr;
                float v = fmaf(rcinv[row], aP[rr], aQ[rr]) + b1v;
                v = (v >= 0.f) ? v : 0.01f * v;
                h1s[row][wn + l16] = f2b(v);
            }
        }
        __syncthreads();   // bar2: h1s ready

        // ==== interval C: prefetch next tile's inputs (fly under GEMM2+epilogue),
        //                  then GEMM2 + fused epilogue ====
        if (tn < NTILES) {
            const int g2 = tn*TILE + r;
            pe  = inv[g2];
            plu = last_update[g2];
            pmc = memory[(size_t)g2*129 + 128];
            const float* mrow2 = memory + (size_t)g2*129 + c0;
            #pragma unroll
            for (int j = 0; j < 16; ++j) pm[j] = mrow2[j];
            if (pe >= 0) {
                pts = uts[pe];
                pgc = umsg[(size_t)pe*129 + 128];
            }
        }
        #pragma unroll
        for (int mt = 0; mt < 4; ++mt) {
            f32x4 acc = {0.f, 0.f, 0.f, 0.f};
            const int mrow = mt*16 + l16;
            #pragma unroll
            for (int k = 0; k < 4; ++k) {
                u16x8 a = *(const u16x8*)&h1s[mrow][k*32 + quad*8];
                acc = __builtin_amdgcn_mfma_f32_16x16x32_bf16(
                        __builtin_bit_cast(bf16x8, a),
                        __builtin_bit_cast(bf16x8, w2f[k]), acc, 0, 0, 0);
            }
            #pragma unroll
            for (int rr = 0; rr < 4; ++rr) {
                const int row = mt*16 + quad*4 + rr;
                const int g = row0 + row;
                float v = acc[rr] + b2v;
                v = (v >= 0.f) ? v : 0.01f * v;
                v *= rscale[par][row];                  // * exp((lu'-now)/OUTPUT)
                const float sv = semb[(size_t)g*128 + wn + l16];
                out[(size_t)g*128 + wn + l16] = el * sv + (1.0f - el) * v;
            }
        }
        // No C->A barrier: msum WAR guarded by bar2 (last readers in B);
        // h1s WAR guarded by next bar1; rscale & s_next parity-buffered.
        tile = tn;
        ++it;
    }
}

extern "C" void kernel_launch(void* const* d_in, const int* in_sizes, int n_in,
                              void* d_out, int out_size, void* d_ws, size_t ws_size,
                              hipStream_t stream) {
    const float* memory      = (const float*)d_in[0];
    const float* last_update = (const float*)d_in[1];
    const float* umsg        = (const float*)d_in[2];
    const float* uts         = (const float*)d_in[3];
    const float* semb        = (const float*)d_in[4];
    const float* W1          = (const float*)d_in[5];
    const float* b1          = (const float*)d_in[6];
    const float* W2          = (const float*)d_in[7];
    const float* b2          = (const float*)d_in[8];
    const float* e_lamb      = (const float*)d_in[9];
    const float* nowt        = (const float*)d_in[10];
    const int*   src         = (const int*)d_in[11];

    int* inv     = (int*)d_ws;            // N ints
    int* counter = inv + N_ROWS;          // 1 int (work-steal)
    float* out   = (float*)d_out;         // fp32 — reference output dtype

    fill_inv<<<(N_ROWS + 255) / 256, 256, 0, stream>>>(inv, counter);
    scatter_inv<<<(E_UPD + 255) / 256, 256, 0, stream>>>(src, inv);
    ctdg_main<<<MAIN_GRID, 512, 0, stream>>>(memory, last_update, umsg, uts, semb,
                                             W1, b1, W2, b2, e_lamb, nowt,
                                             inv, counter, out);
}